// Round 1
// baseline (1605.029 us; speedup 1.0000x reference)
//
#include <hip/hip_runtime.h>

// EncoderSRNN: T=256 steps, B=128, HDIM=EDIM=256, SSZ=64, SDIM=64, SDEPTH=2, NACT=3
// d_out layout (floats): outputs[256][128][256] @0 ; hid[128][256] @8388608 ;
//                        stack[128][64][64] @8421376 ; acts[256][128] @8945664
#define T_STEPS 256
#define BATCH 128

// ws float offsets (transposed weights + combined bias)
#define WEHT_OFF 0         // [e][h] 256x256
#define WHHT_OFF 65536     // [e][h] 256x256
#define WSHT_OFF 131072    // [j][h] 128x256
#define WHST_OFF 163840    // [e][s] 256x64
#define WSUT_OFF 180224    // [j][s] 128x64
#define BC_OFF   188416    // bc[h] = b_eh+b_hh+b_sh
#define WS_FLOATS 188672

#define OUT_OFF   0
#define HID_OFF   8388608
#define STACK_OFF 8421376
#define ACTS_OFF  8945664

// ---------------- kernel 0: transpose weights into ws, fold biases ----------
__global__ __launch_bounds__(256) void prep_kernel(
    const float* __restrict__ W_hh, const float* __restrict__ b_hh,
    const float* __restrict__ W_eh, const float* __restrict__ b_eh,
    const float* __restrict__ W_sh, const float* __restrict__ b_sh,
    const float* __restrict__ W_hs, const float* __restrict__ W_su,
    float* __restrict__ ws)
{
    int idx = blockIdx.x * 256 + threadIdx.x;
    if (idx < 65536) {                       // W_ehT[e][h] = W_eh[h][e]
        ws[WEHT_OFF + idx] = W_eh[(idx & 255) * 256 + (idx >> 8)];
    } else if (idx < 131072) {               // W_hhT
        int k = idx - 65536;
        ws[WHHT_OFF + k] = W_hh[(k & 255) * 256 + (k >> 8)];
    } else if (idx < 163840) {               // W_shT[j][h] = W_sh[h][j]
        int k = idx - 131072;
        ws[WSHT_OFF + k] = W_sh[(k & 255) * 128 + (k >> 8)];
    } else if (idx < 180224) {               // W_hsT[e][s] = W_hs[s][e]
        int k = idx - 163840;
        ws[WHST_OFF + k] = W_hs[(k & 63) * 256 + (k >> 6)];
    } else if (idx < 188416) {               // W_suT[j][s] = W_su[s][j]
        int k = idx - 180224;
        ws[WSUT_OFF + k] = W_su[(k & 63) * 128 + (k >> 6)];
    } else if (idx < 188672) {
        int k = idx - 188416;
        ws[BC_OFF + k] = b_eh[k] + b_hh[k] + b_sh[k];
    }
}

// ---------------- kernel 1: ex[t,b,h] = emb_W[tok]@W_eh.T + bc  -------------
// block: 256 threads, 32 rows x 256 cols; thread t owns column h=t.
__global__ __launch_bounds__(256) void ex_gemm(
    const int* __restrict__ tokens, const float* __restrict__ emb_W,
    const float* __restrict__ ws, float* __restrict__ outp)
{
    __shared__ __align__(16) float aT[64 * 40];   // [e within chunk][row], pad 40
    __shared__ int tok[32];
    const int t = threadIdx.x;
    const int R0 = blockIdx.x * 32;
    if (t < 32) tok[t] = tokens[R0 + t];
    __syncthreads();

    float acc[32];
#pragma unroll
    for (int r = 0; r < 32; r++) acc[r] = 0.f;

    for (int e0 = 0; e0 < 256; e0 += 64) {
        // stage A^T chunk: thread (r=t>>3, seg=t&7) loads 8 floats of row r
        {
            int r = t >> 3, seg = t & 7;
            const float* src = emb_W + (size_t)tok[r] * 256 + e0 + seg * 8;
            float4 v0 = *(const float4*)(src);
            float4 v1 = *(const float4*)(src + 4);
            int eb = seg * 8;
            aT[(eb + 0) * 40 + r] = v0.x; aT[(eb + 1) * 40 + r] = v0.y;
            aT[(eb + 2) * 40 + r] = v0.z; aT[(eb + 3) * 40 + r] = v0.w;
            aT[(eb + 4) * 40 + r] = v1.x; aT[(eb + 5) * 40 + r] = v1.y;
            aT[(eb + 6) * 40 + r] = v1.z; aT[(eb + 7) * 40 + r] = v1.w;
        }
        __syncthreads();
        const float* wp = ws + WEHT_OFF + (size_t)e0 * 256 + t;
#pragma unroll 4
        for (int e = 0; e < 64; e++) {
            float wv = wp[(size_t)e * 256];               // coalesced across t
            const float4* arow = (const float4*)&aT[e * 40]; // broadcast reads
#pragma unroll
            for (int j = 0; j < 8; j++) {
                float4 a4 = arow[j];
                acc[j * 4 + 0] = fmaf(a4.x, wv, acc[j * 4 + 0]);
                acc[j * 4 + 1] = fmaf(a4.y, wv, acc[j * 4 + 1]);
                acc[j * 4 + 2] = fmaf(a4.z, wv, acc[j * 4 + 2]);
                acc[j * 4 + 3] = fmaf(a4.w, wv, acc[j * 4 + 3]);
            }
        }
        __syncthreads();
    }
    float bcv = ws[BC_OFF + t];
#pragma unroll
    for (int r = 0; r < 32; r++)
        outp[(size_t)(R0 + r) * 256 + t] = acc[r] + bcv;
}

// ---------------- kernel 2: the sequential scan -----------------------------
// 64 blocks x 512 threads; block handles batch pair (2*blk, 2*blk+1).
// Interleaved LDS state: hid2[h*2+el], tops2[j*2+el]; stack per elem in LDS.
__global__ __launch_bounds__(512) void rnn_scan(
    const float* __restrict__ ws,
    const float* __restrict__ W_ha, const float* __restrict__ b_ha,
    const float* __restrict__ W_hg, const float* __restrict__ b_hg,
    const float* __restrict__ b_hs, const float* __restrict__ b_su,
    const float* __restrict__ empty_elem,
    float* __restrict__ out)
{
    __shared__ __align__(16) float stk[2 * 4096];       // 32 KB
    __shared__ __align__(16) float partial[8 * 2 * 256]; // 16 KB  [w][el][h]
    __shared__ __align__(16) float hid2[2 * 256];       // [h][el]
    __shared__ __align__(16) float tops2[2 * 128];      // [j][el]
    __shared__ __align__(16) float ppb[8 * 2 * 64];     // push partials [w][el][s]
    __shared__ __align__(16) float pub[8 * 2 * 64];     // u partials
    __shared__ float pv2[2 * 64];                       // push_val [s][el]
    __shared__ float uv2[2 * 64];                       // u_val    [s][el]
    __shared__ float scal[8];                           // l0,l1,l2,g per el

    const float* WhhT = ws + WHHT_OFF;
    const float* WshT = ws + WSHT_OFF;
    const float* WhsT = ws + WHST_OFF;
    const float* WsuT = ws + WSUT_OFF;

    const int t    = threadIdx.x;
    const int lane = t & 63;
    const int w    = t >> 6;          // wave 0..7
    const int blk  = blockIdx.x;

    const int el  = t >> 8;           // elem (0/1) for reduce/stack phases
    const int hh  = t & 255;          // hidden index
    const int myb = blk * 2 + el;
    const int c   = t & 63;           // stack col
    const int r0g = ((t >> 6) & 3) * 16; // stack row base (16 consecutive rows)
    const int h4  = lane * 4;

    // ---- init state
    hid2[t] = 0.f;
    if (t < 256) tops2[t] = empty_elem[(t >> 1) & 63];
#pragma unroll
    for (int k = 0; k < 16; k++)
        stk[el * 4096 + (t & 255) + k * 256] = empty_elem[c];
    __syncthreads();

    for (int ts = 0; ts < T_STEPS; ts++) {
        // ======== phase A: mhid partial GEMV (W_hh: e in [32w,32w+32), W_sh: j in [16w,16w+16))
        float a00=0,a01=0,a10=0,a11=0,a20=0,a21=0,a30=0,a31=0;
        {
            const float* wp = WhhT + (size_t)(w * 32) * 256 + h4;
#pragma unroll 4
            for (int e = 0; e < 32; e++) {
                float4 wv = *(const float4*)(wp);
                float2 hv = *(const float2*)&hid2[(w * 32 + e) * 2];
                a00 = fmaf(wv.x, hv.x, a00); a01 = fmaf(wv.x, hv.y, a01);
                a10 = fmaf(wv.y, hv.x, a10); a11 = fmaf(wv.y, hv.y, a11);
                a20 = fmaf(wv.z, hv.x, a20); a21 = fmaf(wv.z, hv.y, a21);
                a30 = fmaf(wv.w, hv.x, a30); a31 = fmaf(wv.w, hv.y, a31);
                wp += 256;
            }
            const float* wp2 = WshT + (size_t)(w * 16) * 256 + h4;
#pragma unroll 4
            for (int j = 0; j < 16; j++) {
                float4 wv = *(const float4*)(wp2);
                float2 tv = *(const float2*)&tops2[(w * 16 + j) * 2];
                a00 = fmaf(wv.x, tv.x, a00); a01 = fmaf(wv.x, tv.y, a01);
                a10 = fmaf(wv.y, tv.x, a10); a11 = fmaf(wv.y, tv.y, a11);
                a20 = fmaf(wv.z, tv.x, a20); a21 = fmaf(wv.z, tv.y, a21);
                a30 = fmaf(wv.w, tv.x, a30); a31 = fmaf(wv.w, tv.y, a31);
                wp2 += 256;
            }
        }
        *(float4*)&partial[(w * 2 + 0) * 256 + h4] = make_float4(a00, a10, a20, a30);
        *(float4*)&partial[(w * 2 + 1) * 256 + h4] = make_float4(a01, a11, a21, a31);

        // ======== phase B: act logits + gamma dots (one dot per wave, old hid)
        {
            int elw = w >> 2, row = w & 3;
            const float* vec = (row < 3) ? (W_ha + row * 256) : W_hg;
            float bd = 0.f;
#pragma unroll
            for (int k2 = 0; k2 < 4; k2++) {
                int e = lane + k2 * 64;
                bd = fmaf(vec[e], hid2[e * 2 + elw], bd);
            }
#pragma unroll
            for (int off = 32; off > 0; off >>= 1) bd += __shfl_down(bd, off);
            if (lane == 0) scal[w] = bd + ((row < 3) ? b_ha[row] : b_hg[0]);
        }

        // ======== phase B2: push_val / u_val partial dots (both elems per load)
        {
            float dpA = 0, dpB = 0, duA = 0, duB = 0;
            const float* wp = WhsT + (size_t)(w * 32) * 64 + lane;
#pragma unroll 4
            for (int e = 0; e < 32; e++) {
                float wv = *wp;
                float2 hv = *(const float2*)&hid2[(w * 32 + e) * 2];
                dpA = fmaf(wv, hv.x, dpA); dpB = fmaf(wv, hv.y, dpB);
                wp += 64;
            }
            const float* wp2 = WsuT + (size_t)(w * 16) * 64 + lane;
#pragma unroll 4
            for (int j = 0; j < 16; j++) {
                float wv = *wp2;
                float2 tv = *(const float2*)&tops2[(w * 16 + j) * 2];
                duA = fmaf(wv, tv.x, duA); duB = fmaf(wv, tv.y, duB);
                wp2 += 64;
            }
            ppb[(w * 2 + 0) * 64 + lane] = dpA;
            ppb[(w * 2 + 1) * 64 + lane] = dpB;
            pub[(w * 2 + 0) * 64 + lane] = duA;
            pub[(w * 2 + 1) * 64 + lane] = duB;
        }

        __syncthreads(); // s1: partial/scal/ppb/pub ready

        // ---- A-reduce: mhid -> new_hid (ex staged in out[] by ex_gemm)
        float mh = out[((size_t)ts * BATCH + myb) * 256 + hh];
#pragma unroll
        for (int q = 0; q < 8; q++) mh += partial[q * 512 + el * 256 + hh];
        float nh = fmaxf(mh, 0.f);

        // ---- B3: finalize push_val / u_val
        if (t < 128) {
            int e2 = t >> 6, s = t & 63;
            float v = b_hs[s];
#pragma unroll
            for (int q = 0; q < 8; q++) v += ppb[(q * 2 + e2) * 64 + s];
            pv2[s * 2 + e2] = fmaxf(v, 0.f);
        } else if (t < 256) {
            int tt = t - 128; int e2 = tt >> 6, s = tt & 63;
            float v = b_su[s];
#pragma unroll
            for (int q = 0; q < 8; q++) v += pub[(q * 2 + e2) * 64 + s];
            uv2[s * 2 + e2] = fmaxf(v, 0.f);
        }

        // ---- softmax -> sharpen -> p's (redundant per thread, own elem)
        float l0 = scal[el * 4 + 0], l1 = scal[el * 4 + 1];
        float l2 = scal[el * 4 + 2], gv = scal[el * 4 + 3];
        float g = 1.f + ((gv > 15.f) ? gv : log1pf(expf(gv)));
        float m = fmaxf(l0, fmaxf(l1, l2));
        float z = expf(l0 - m) + expf(l1 - m) + expf(l2 - m);
        float lz = logf(z);
        float s0 = expf(g * (l0 - m - lz));
        float s1v = expf(g * (l1 - m - lz));
        float s2v = expf(g * (l2 - m - lz));
        float S = s0 + s1v + s2v + 1e-16f;
        float p0 = s0 / S, p1 = s1v / S, p2 = s2v / S;
        if (hh == 0) {
            int am = 0; float bm = s0;
            if (s1v > bm) { bm = s1v; am = 1; }
            if (s2v > bm) { bm = s2v; am = 2; }
            out[ACTS_OFF + ts * BATCH + myb] = (float)am;
        }

        // ---- stack read (old values into regs); rows r0g..r0g+15, col c
        float sv[18];
        const float* Sb = &stk[el * 4096];
#pragma unroll
        for (int k = 0; k < 16; k++) sv[k + 1] = Sb[(r0g + k) * 64 + c];
        sv[0]  = (r0g == 0)  ? 0.f : Sb[(r0g - 1) * 64 + c];
        sv[17] = (r0g == 48) ? 0.f : Sb[(r0g + 16) * 64 + c];

        __syncthreads(); // s2: all old-state reads done; pv2/uv2 published

        float pvv = pv2[c * 2 + el];
        float uvv = uv2[c * 2 + el];
        float* Sw = &stk[el * 4096];
#pragma unroll
        for (int k = 0; k < 16; k++) {
            int r = r0g + k;
            float below = (r == 0) ? pvv : sv[k];     // push source (s[r-1])
            float above = sv[k + 2];                  // s[r+1]; r==63 -> 0
            float popv  = (r == 0) ? uvv : above;     // pop source
            float nsv = p0 * below + p1 * popv + p2 * sv[k + 1];
            Sw[r * 64 + c] = nsv;
            if (r < 2) tops2[(r * 64 + c) * 2 + el] = nsv;
        }
        hid2[hh * 2 + el] = nh;
        out[((size_t)ts * BATCH + myb) * 256 + hh] = nh;  // overwrite ex slot

        __syncthreads(); // s3: new state visible for next step
    }

    // ---- final hid & stack
    out[HID_OFF + (size_t)myb * 256 + hh] = hid2[hh * 2 + el];
#pragma unroll
    for (int k = 0; k < 16; k++) {
        int r = r0g + k;
        out[STACK_OFF + (size_t)myb * 4096 + r * 64 + c] = stk[el * 4096 + r * 64 + c];
    }
}

// ---------------- launcher ---------------------------------------------------
extern "C" void kernel_launch(void* const* d_in, const int* in_sizes, int n_in,
                              void* d_out, int out_size, void* d_ws, size_t ws_size,
                              hipStream_t stream)
{
    (void)in_sizes; (void)n_in; (void)out_size; (void)ws_size;
    const int*   inputs     = (const int*)d_in[0];
    const float* emb_W      = (const float*)d_in[1];
    const float* W_hh       = (const float*)d_in[2];
    const float* b_hh       = (const float*)d_in[3];
    const float* W_eh       = (const float*)d_in[4];
    const float* b_eh       = (const float*)d_in[5];
    const float* W_ha       = (const float*)d_in[6];
    const float* b_ha       = (const float*)d_in[7];
    const float* W_hg       = (const float*)d_in[8];
    const float* b_hg       = (const float*)d_in[9];
    const float* W_hs       = (const float*)d_in[10];
    const float* b_hs       = (const float*)d_in[11];
    const float* W_sh       = (const float*)d_in[12];
    const float* b_sh       = (const float*)d_in[13];
    const float* W_su       = (const float*)d_in[14];
    const float* b_su       = (const float*)d_in[15];
    const float* empty_elem = (const float*)d_in[16];
    float* out = (float*)d_out;
    float* ws  = (float*)d_ws;

    hipLaunchKernelGGL(prep_kernel, dim3(737), dim3(256), 0, stream,
                       W_hh, b_hh, W_eh, b_eh, W_sh, b_sh, W_hs, W_su, ws);
    hipLaunchKernelGGL(ex_gemm, dim3(1024), dim3(256), 0, stream,
                       inputs, emb_W, ws, out);
    hipLaunchKernelGGL(rnn_scan, dim3(64), dim3(512), 0, stream,
                       ws, W_ha, b_ha, W_hg, b_hg, b_hs, b_su, empty_elem, out);
}

// Round 3
// 1107.674 us; speedup vs baseline: 1.4490x; 1.4490x over previous
//
#include <hip/hip_runtime.h>

// EncoderSRNN: T=256 steps, B=128, HDIM=EDIM=256, SSZ=64, SDIM=64, SDEPTH=2, NACT=3
#define T_STEPS 256
#define BATCH 128

// ws float offsets (transposed weights + combined bias)
#define WEHT_OFF 0         // [e][h] 256x256
#define WHHT_OFF 65536     // [e][h] 256x256
#define WSHT_OFF 131072    // [j][h] 128x256
#define WHST_OFF 163840    // [e][s] 256x64
#define WSUT_OFF 180224    // [j][s] 128x64
#define BC_OFF   188416    // bc[h] = b_eh+b_hh+b_sh

#define HID_OFF   8388608
#define STACK_OFF 8421376
#define ACTS_OFF  8945664

// ---------------- kernel 0: transpose weights into ws, fold biases ----------
__global__ __launch_bounds__(256) void prep_kernel(
    const float* __restrict__ W_hh, const float* __restrict__ b_hh,
    const float* __restrict__ W_eh, const float* __restrict__ b_eh,
    const float* __restrict__ W_sh, const float* __restrict__ b_sh,
    const float* __restrict__ W_hs, const float* __restrict__ W_su,
    float* __restrict__ ws)
{
    int idx = blockIdx.x * 256 + threadIdx.x;
    if (idx < 65536) {                       // W_ehT[e][h] = W_eh[h][e]
        ws[WEHT_OFF + idx] = W_eh[(idx & 255) * 256 + (idx >> 8)];
    } else if (idx < 131072) {               // W_hhT
        int k = idx - 65536;
        ws[WHHT_OFF + k] = W_hh[(k & 255) * 256 + (k >> 8)];
    } else if (idx < 163840) {               // W_shT[j][h] = W_sh[h][j]
        int k = idx - 131072;
        ws[WSHT_OFF + k] = W_sh[(k & 255) * 128 + (k >> 8)];
    } else if (idx < 180224) {               // W_hsT[e][s] = W_hs[s][e]
        int k = idx - 163840;
        ws[WHST_OFF + k] = W_hs[(k & 63) * 256 + (k >> 6)];
    } else if (idx < 188416) {               // W_suT[j][s] = W_su[s][j]
        int k = idx - 180224;
        ws[WSUT_OFF + k] = W_su[(k & 63) * 128 + (k >> 6)];
    } else if (idx < 188672) {
        int k = idx - 188416;
        ws[BC_OFF + k] = b_eh[k] + b_hh[k] + b_sh[k];
    }
}

// ---------------- kernel 1: ex[t,b,h] = emb_W[tok]@W_eh.T + bc  -------------
__global__ __launch_bounds__(256) void ex_gemm(
    const int* __restrict__ tokens, const float* __restrict__ emb_W,
    const float* __restrict__ ws, float* __restrict__ outp)
{
    __shared__ __align__(16) float aT[64 * 40];
    __shared__ int tok[32];
    const int t = threadIdx.x;
    const int R0 = blockIdx.x * 32;
    if (t < 32) tok[t] = tokens[R0 + t];
    __syncthreads();

    float acc[32];
#pragma unroll
    for (int r = 0; r < 32; r++) acc[r] = 0.f;

    for (int e0 = 0; e0 < 256; e0 += 64) {
        {
            int r = t >> 3, seg = t & 7;
            const float* src = emb_W + (size_t)tok[r] * 256 + e0 + seg * 8;
            float4 v0 = *(const float4*)(src);
            float4 v1 = *(const float4*)(src + 4);
            int eb = seg * 8;
            aT[(eb + 0) * 40 + r] = v0.x; aT[(eb + 1) * 40 + r] = v0.y;
            aT[(eb + 2) * 40 + r] = v0.z; aT[(eb + 3) * 40 + r] = v0.w;
            aT[(eb + 4) * 40 + r] = v1.x; aT[(eb + 5) * 40 + r] = v1.y;
            aT[(eb + 6) * 40 + r] = v1.z; aT[(eb + 7) * 40 + r] = v1.w;
        }
        __syncthreads();
        const float* wp = ws + WEHT_OFF + (size_t)e0 * 256 + t;
#pragma unroll 4
        for (int e = 0; e < 64; e++) {
            float wv = wp[(size_t)e * 256];
            const float4* arow = (const float4*)&aT[e * 40];
#pragma unroll
            for (int j = 0; j < 8; j++) {
                float4 a4 = arow[j];
                acc[j * 4 + 0] = fmaf(a4.x, wv, acc[j * 4 + 0]);
                acc[j * 4 + 1] = fmaf(a4.y, wv, acc[j * 4 + 1]);
                acc[j * 4 + 2] = fmaf(a4.z, wv, acc[j * 4 + 2]);
                acc[j * 4 + 3] = fmaf(a4.w, wv, acc[j * 4 + 3]);
            }
        }
        __syncthreads();
    }
    float bcv = ws[BC_OFF + t];
#pragma unroll
    for (int r = 0; r < 32; r++)
        outp[(size_t)(R0 + r) * 256 + t] = acc[r] + bcv;
}

// ---------------- kernel 2: the sequential scan (register-resident weights) --
// 128 blocks x 512 threads; block b handles batch elem b.
// Thread (w = t>>6, lane = t&63):
//   phase A: owns cols h=lane*4..+3, e-range [w*32,w*32+32) (W_hh) / j [w*16,+16) (W_sh)
//   phase B2: owns s=lane, same e/j ranges (W_hs regs, W_su via packed LDS)
//   stack: rows w*8..w*8+8, col lane.
__global__ __launch_bounds__(512, 2) void rnn_scan(
    const float* __restrict__ ws,
    const float* __restrict__ W_ha, const float* __restrict__ b_ha,
    const float* __restrict__ W_hg, const float* __restrict__ b_hg,
    const float* __restrict__ b_hs, const float* __restrict__ b_su,
    const float* __restrict__ empty_elem,
    float* __restrict__ out)
{
    __shared__ __align__(16) float stk[4096];      // 16 KB
    __shared__ __align__(16) float hid[256];
    __shared__ __align__(16) float tops[128];
    __shared__ __align__(16) float partial[8 * 256]; // 8 KB
    __shared__ __align__(16) float ppb[8 * 64];
    __shared__ __align__(16) float pub[8 * 64];
    __shared__ __align__(16) float wsu_l[8192];    // 32 KB, packed [j>>2][s][j&3]
    __shared__ __align__(16) float whaL[1024];     // rows 0-2: W_ha, row 3: W_hg
    __shared__ float pv2[64], uv2[64], scal[4];

    const int t = threadIdx.x, lane = t & 63, w = t >> 6;
    const int b = blockIdx.x;

    // ---- weight registers (loaded once; all use sites fully unrolled)
    float4 whh[32], wsh[16];
    float  whs[32];
    {
        const float* base = ws + WHHT_OFF + (size_t)(w * 32) * 256 + lane * 4;
#pragma unroll
        for (int e = 0; e < 32; e++) whh[e] = *(const float4*)(base + (size_t)e * 256);
        const float* base2 = ws + WSHT_OFF + (size_t)(w * 16) * 256 + lane * 4;
#pragma unroll
        for (int j = 0; j < 16; j++) wsh[j] = *(const float4*)(base2 + (size_t)j * 256);
        const float* base3 = ws + WHST_OFF + (size_t)(w * 32) * 64 + lane;
#pragma unroll
        for (int e = 0; e < 32; e++) whs[e] = base3[(size_t)e * 64];
    }
    // per-role bias registers
    float bscal = 0.f;
    if (lane == 0 && w < 4) bscal = (w < 3) ? b_ha[w] : b_hg[0];
    float bhs_r = (t >= 256 && t < 320) ? b_hs[t - 256] : 0.f;
    float bsu_r = (t >= 320 && t < 384) ? b_su[t - 320] : 0.f;

    // ---- init LDS state + LDS-resident small weights
    for (int i = t; i < 4096; i += 512) stk[i] = empty_elem[i & 63];
    if (t < 256) hid[t] = 0.f;
    if (t < 128) tops[t] = empty_elem[t & 63];
    for (int i = t; i < 8192; i += 512) {
        int j = i >> 6, s = i & 63;
        wsu_l[(j >> 2) * 256 + s * 4 + (j & 3)] = ws[WSUT_OFF + i];
    }
    for (int i = t; i < 1024; i += 512)
        whaL[i] = (i < 768) ? W_ha[i] : W_hg[i - 768];
    __syncthreads();

    for (int ts = 0; ts < T_STEPS; ts++) {
        // prefetch ex (consumed after s1; latency hidden by phase-A FMAs)
        float exv = 0.f;
        if (t < 256) exv = out[((size_t)ts * BATCH + b) * 256 + t];

        // ======== phase A + B2 fused: all dot-product partials from old state
        float4 acc = make_float4(0.f, 0.f, 0.f, 0.f);
        float accP = 0.f, accU = 0.f;
#pragma unroll
        for (int eb = 0; eb < 8; eb++) {
            float4 hv = *(const float4*)&hid[w * 32 + eb * 4];
            acc.x = fmaf(whh[eb*4+0].x, hv.x, acc.x); acc.y = fmaf(whh[eb*4+0].y, hv.x, acc.y);
            acc.z = fmaf(whh[eb*4+0].z, hv.x, acc.z); acc.w = fmaf(whh[eb*4+0].w, hv.x, acc.w);
            acc.x = fmaf(whh[eb*4+1].x, hv.y, acc.x); acc.y = fmaf(whh[eb*4+1].y, hv.y, acc.y);
            acc.z = fmaf(whh[eb*4+1].z, hv.y, acc.z); acc.w = fmaf(whh[eb*4+1].w, hv.y, acc.w);
            acc.x = fmaf(whh[eb*4+2].x, hv.z, acc.x); acc.y = fmaf(whh[eb*4+2].y, hv.z, acc.y);
            acc.z = fmaf(whh[eb*4+2].z, hv.z, acc.z); acc.w = fmaf(whh[eb*4+2].w, hv.z, acc.w);
            acc.x = fmaf(whh[eb*4+3].x, hv.w, acc.x); acc.y = fmaf(whh[eb*4+3].y, hv.w, acc.y);
            acc.z = fmaf(whh[eb*4+3].z, hv.w, acc.z); acc.w = fmaf(whh[eb*4+3].w, hv.w, acc.w);
            accP = fmaf(whs[eb*4+0], hv.x, accP);
            accP = fmaf(whs[eb*4+1], hv.y, accP);
            accP = fmaf(whs[eb*4+2], hv.z, accP);
            accP = fmaf(whs[eb*4+3], hv.w, accP);
        }
#pragma unroll
        for (int jb = 0; jb < 4; jb++) {
            float4 tv = *(const float4*)&tops[w * 16 + jb * 4];
            acc.x = fmaf(wsh[jb*4+0].x, tv.x, acc.x); acc.y = fmaf(wsh[jb*4+0].y, tv.x, acc.y);
            acc.z = fmaf(wsh[jb*4+0].z, tv.x, acc.z); acc.w = fmaf(wsh[jb*4+0].w, tv.x, acc.w);
            acc.x = fmaf(wsh[jb*4+1].x, tv.y, acc.x); acc.y = fmaf(wsh[jb*4+1].y, tv.y, acc.y);
            acc.z = fmaf(wsh[jb*4+1].z, tv.y, acc.z); acc.w = fmaf(wsh[jb*4+1].w, tv.y, acc.w);
            acc.x = fmaf(wsh[jb*4+2].x, tv.z, acc.x); acc.y = fmaf(wsh[jb*4+2].y, tv.z, acc.y);
            acc.z = fmaf(wsh[jb*4+2].z, tv.z, acc.z); acc.w = fmaf(wsh[jb*4+2].w, tv.z, acc.w);
            acc.x = fmaf(wsh[jb*4+3].x, tv.w, acc.x); acc.y = fmaf(wsh[jb*4+3].y, tv.w, acc.y);
            acc.z = fmaf(wsh[jb*4+3].z, tv.w, acc.z); acc.w = fmaf(wsh[jb*4+3].w, tv.w, acc.w);
            float4 su = *(const float4*)&wsu_l[(w * 4 + jb) * 256 + lane * 4];
            accU = fmaf(su.x, tv.x, accU);
            accU = fmaf(su.y, tv.y, accU);
            accU = fmaf(su.z, tv.z, accU);
            accU = fmaf(su.w, tv.w, accU);
        }
        *(float4*)&partial[w * 256 + lane * 4] = acc;
        ppb[w * 64 + lane] = accP;
        pub[w * 64 + lane] = accU;

        // ======== phase B: act logits + gamma dots (waves 0..3, old hid)
        if (w < 4) {
            float bd = 0.f;
#pragma unroll
            for (int k = 0; k < 4; k++)
                bd = fmaf(whaL[w * 256 + k * 64 + lane], hid[k * 64 + lane], bd);
#pragma unroll
            for (int off = 32; off > 0; off >>= 1) bd += __shfl_down(bd, off);
            if (lane == 0) scal[w] = bd + bscal;
        }
        __syncthreads(); // s1

        // ---- softmax -> sharpen (all threads, wave-uniform scal broadcast)
        float l0 = scal[0], l1 = scal[1], l2 = scal[2], gv = scal[3];
        float g = 1.f + ((gv > 15.f) ? gv : log1pf(expf(gv)));
        float m = fmaxf(l0, fmaxf(l1, l2));
        float z = expf(l0 - m) + expf(l1 - m) + expf(l2 - m);
        float lz = logf(z);
        float s0  = expf(g * (l0 - m - lz));
        float s1v = expf(g * (l1 - m - lz));
        float s2v = expf(g * (l2 - m - lz));
        float S = s0 + s1v + s2v + 1e-16f;
        float p0 = s0 / S, p1 = s1v / S, p2 = s2v / S;

        // ---- read old stack rows (w*8-1 .. w*8+8) into regs
        float sv[10];
        sv[0] = (w == 0) ? 0.f : stk[(w * 8 - 1) * 64 + lane];
#pragma unroll
        for (int k = 0; k < 8; k++) sv[k + 1] = stk[(w * 8 + k) * 64 + lane];
        sv[9] = (w == 7) ? 0.f : stk[(w * 8 + 8) * 64 + lane];

        // ---- reduce phases (parallel thread roles)
        if (t < 256) {
            float mh = exv;
#pragma unroll
            for (int q = 0; q < 8; q++) mh += partial[q * 256 + t];
            float nh = fmaxf(mh, 0.f);
            hid[t] = nh;                                    // old hid dead after s1
            out[((size_t)ts * BATCH + b) * 256 + t] = nh;
        } else if (t < 320) {
            int s = t - 256; float v = bhs_r;
#pragma unroll
            for (int q = 0; q < 8; q++) v += ppb[q * 64 + s];
            pv2[s] = fmaxf(v, 0.f);
        } else if (t < 384) {
            int s = t - 320; float v = bsu_r;
#pragma unroll
            for (int q = 0; q < 8; q++) v += pub[q * 64 + s];
            uv2[s] = fmaxf(v, 0.f);
        }
        if (t == 0) {
            int am = 0; float bm = s0;
            if (s1v > bm) { bm = s1v; am = 1; }
            if (s2v > bm) { bm = s2v; am = 2; }
            out[ACTS_OFF + ts * BATCH + b] = (float)am;
        }
        __syncthreads(); // s2: pv2/uv2 ready; all old-stack reads done

        // ---- stack blend (in-place; reads were staged to regs)
        float pvv = pv2[lane], uvv = uv2[lane];
#pragma unroll
        for (int k = 0; k < 8; k++) {
            int r = w * 8 + k;
            float below = (r == 0) ? pvv : sv[k];   // push source s[r-1]
            float above = sv[k + 2];                // s[r+1]; r==63 -> sv[9]=0
            float popv  = (r == 0) ? uvv : above;   // pop source
            float ns = fmaf(p0, below, fmaf(p1, popv, p2 * sv[k + 1]));
            stk[r * 64 + lane] = ns;
            if (r < 2) tops[r * 64 + lane] = ns;
        }
        __syncthreads(); // s3: new state visible for next step
    }

    // ---- final hid & stack
    if (t < 256) out[HID_OFF + (size_t)b * 256 + t] = hid[t];
#pragma unroll
    for (int k = 0; k < 8; k++) {
        int r = w * 8 + k;
        out[STACK_OFF + (size_t)b * 4096 + r * 64 + lane] = stk[r * 64 + lane];
    }
}

// ---------------- launcher ---------------------------------------------------
extern "C" void kernel_launch(void* const* d_in, const int* in_sizes, int n_in,
                              void* d_out, int out_size, void* d_ws, size_t ws_size,
                              hipStream_t stream)
{
    (void)in_sizes; (void)n_in; (void)out_size; (void)ws_size;
    const int*   inputs     = (const int*)d_in[0];
    const float* emb_W      = (const float*)d_in[1];
    const float* W_hh       = (const float*)d_in[2];
    const float* b_hh       = (const float*)d_in[3];
    const float* W_eh       = (const float*)d_in[4];
    const float* b_eh       = (const float*)d_in[5];
    const float* W_ha       = (const float*)d_in[6];
    const float* b_ha       = (const float*)d_in[7];
    const float* W_hg       = (const float*)d_in[8];
    const float* b_hg       = (const float*)d_in[9];
    const float* W_hs       = (const float*)d_in[10];
    const float* b_hs       = (const float*)d_in[11];
    const float* W_sh       = (const float*)d_in[12];
    const float* b_sh       = (const float*)d_in[13];
    const float* W_su       = (const float*)d_in[14];
    const float* b_su       = (const float*)d_in[15];
    const float* empty_elem = (const float*)d_in[16];
    float* out = (float*)d_out;
    float* ws  = (float*)d_ws;

    hipLaunchKernelGGL(prep_kernel, dim3(737), dim3(256), 0, stream,
                       W_hh, b_hh, W_eh, b_eh, W_sh, b_sh, W_hs, W_su, ws);
    hipLaunchKernelGGL(ex_gemm, dim3(1024), dim3(256), 0, stream,
                       inputs, emb_W, ws, out);
    hipLaunchKernelGGL(rnn_scan, dim3(128), dim3(512), 0, stream,
                       ws, W_ha, b_ha, W_hg, b_hg, b_hs, b_su, empty_elem, out);
}